// Round 5
// baseline (213.603 us; speedup 1.0000x reference)
//
#include <hip/hip_runtime.h>
#include <hip/hip_bf16.h>

#define EPSBN 1e-5f

typedef short short8 __attribute__((ext_vector_type(8)));
typedef short short4v __attribute__((ext_vector_type(4)));
typedef float f32x16 __attribute__((ext_vector_type(16)));

static __device__ __forceinline__ unsigned short f2u(float f){
  __hip_bfloat16 h = __float2bfloat16(f);
  union { __hip_bfloat16 h; unsigned short u; } c; c.h = h; return c.u;
}

// ---- workspace layout (bytes) ----
#define WS_G     2048
#define WS_S     7168
#define WS_T     8192
#define WS_AGGB  16384      // 147456 bf16  [b][cc2][s9][o32][ci32]
#define WS_XUP   327680     // 33554432 bf16 [b][h16(4)][r256][c256][ci16]  (plane = 1<<20 halfwords)

#define XIN_S 820           // per-ci float stride (820%4==0 for float4; 2*820 % 32 = 8 -> 2-way banks)

// ------- K1: bilinear x2 upsample -> bf16 planes [b][h16][r][c][ci16], GAP fused -------
// grid: 1024 = b(8) x h16(4) x strip(32 of 8 rows)   [proven round-1 version]
__global__ __launch_bounds__(256) void k_up(const float* __restrict__ x,
                                            unsigned int* __restrict__ xup32,
                                            float* __restrict__ g)
{
  __shared__ float xin[16*XIN_S];   // [ci16][ir6][j136: 128 data + 8 zero pad]
  __shared__ float w[128];
  int tid = threadIdx.x;
  int bi  = blockIdx.x;
  int strip = bi & 31, h16 = (bi >> 5) & 3, b = bi >> 7;
  int r0 = strip * 8;
  int i0b = (int)((float)r0 * (127.0f/255.0f));

  if (tid < 128){
    int i = tid;
    float s = 0.f;
    int rstart = max(0, (int)floorf((float)(i-1)*(255.0f/127.0f)));
    #pragma unroll
    for (int k = 0; k < 8; ++k){
      int r = rstart + k;
      if (r <= 255){
        float pos = (float)r * (127.0f/255.0f);
        int i0 = (int)pos; float fr = pos - (float)i0; int i1 = min(i0+1,127);
        if (i0 == i) s += 1.0f - fr;
        if (i1 == i) s += fr;
      }
    }
    w[i] = s;
  }
  for (int e4 = tid; e4 < 3072; e4 += 256){
    int j4 = e4 & 31, ci = (e4 >> 5) & 15, ir = e4 >> 9;
    int row = min(i0b + ir, 127);
    *(float4*)&xin[ci*XIN_S + ir*136 + j4*4] =
      *(const float4*)&x[(((size_t)(b*64 + h16*16 + ci)) << 14) + (row << 7) + j4*4];
  }
  for (int e2 = tid; e2 < 768; e2 += 256){
    int k = e2 & 7, t8 = e2 >> 3;
    int ir = t8 % 6, ci = t8 / 6;
    xin[ci*XIN_S + ir*136 + 128 + k] = 0.f;
  }
  __syncthreads();

  {
    int ci_l = tid >> 4, kk = tid & 15;
    float s = 0.f;
    const float* base = &xin[ci_l*XIN_S];
    #pragma unroll
    for (int row = 0; row < 4; ++row){
      int grow = 4*strip + row;
      int ir = grow - i0b;
      const float* rp = base + ir*136 + kk*8;
      float ss = 0.f;
      #pragma unroll
      for (int j = 0; j < 8; ++j) ss += rp[j]*w[kk*8+j];
      s += w[grow]*ss;
    }
    s += __shfl_down(s, 8, 16);
    s += __shfl_down(s, 4, 16);
    s += __shfl_down(s, 2, 16);
    s += __shfl_down(s, 1, 16);
    if (kk == 0) atomicAdd(&g[b*64 + h16*16 + ci_l], s*(1.0f/65536.0f));
  }

  int ci2 = tid & 7, cbase = tid >> 3;
  const float* b0p = &xin[(ci2*2+0)*XIN_S];
  const float* b1p = &xin[(ci2*2+1)*XIN_S];
  size_t plane32 = ((size_t)(b*4 + h16)) << 19;

  #pragma unroll
  for (int jj = 0; jj < 8; ++jj){
    int c = cbase + 32*jj;
    float pos = (float)c * (127.0f/255.0f);
    int j0 = (int)pos; float ww = pos - (float)j0;

    int irA = 0;
    float A0, B0, A1, B1;
    {
      float x0 = b0p[j0],     x1 = b0p[j0+1];     A0 = x0 + (x1-x0)*ww;
      float y0 = b1p[j0],     y1 = b1p[j0+1];     A1 = y0 + (y1-y0)*ww;
      float x2 = b0p[136+j0], x3 = b0p[136+j0+1]; B0 = x2 + (x3-x2)*ww;
      float y2 = b1p[136+j0], y3 = b1p[136+j0+1]; B1 = y2 + (y3-y2)*ww;
    }
    #pragma unroll
    for (int rr = 0; rr < 8; ++rr){
      int r = r0 + rr;
      float posr = (float)r * (127.0f/255.0f);
      int i0 = (int)posr; float wh = posr - (float)i0;
      int ir0 = i0 - i0b;
      if (ir0 > irA){                 // wave-uniform branch
        A0 = B0; A1 = B1;
        int irB = ir0 + 1;
        float x0 = b0p[irB*136+j0], x1 = b0p[irB*136+j0+1]; B0 = x0 + (x1-x0)*ww;
        float y0 = b1p[irB*136+j0], y1 = b1p[irB*136+j0+1]; B1 = y0 + (y1-y0)*ww;
        irA = ir0;
      }
      float r0v = A0 + (B0-A0)*wh;
      float r1v = A1 + (B1-A1)*wh;
      unsigned pack = (unsigned)f2u(r0v) | (((unsigned)f2u(r1v)) << 16);
      xup32[plane32 + (size_t)(r*256 + c)*8 + ci2] = pack;
    }
  }
}

// ------- K2: attention MLP (redundant per block) + aggregated bf16 filters -------
__global__ __launch_bounds__(256) void k_aggw(const float* __restrict__ g,
                      const float* __restrict__ fc_w,
                      const float* __restrict__ bga, const float* __restrict__ bba,
                      const float* __restrict__ bma, const float* __restrict__ bva,
                      const float* __restrict__ ch_w, const float* __restrict__ ch_b,
                      const float* __restrict__ fil_w, const float* __restrict__ fil_b,
                      const float* __restrict__ sp_w, const float* __restrict__ sp_b,
                      const float* __restrict__ k_w, const float* __restrict__ k_b,
                      const float* __restrict__ bn_g, const float* __restrict__ bn_b,
                      const float* __restrict__ bn_m, const float* __restrict__ bn_v,
                      const float* __restrict__ weight,
                      unsigned short* __restrict__ aggb,
                      float* __restrict__ sS, float* __restrict__ tT)
{
  __shared__ float h[8][16];
  int tid = threadIdx.x;
  if (tid < 128){
    int b = tid >> 4, a = tid & 15;
    float acc = 0.f;
    for (int c = 0; c < 64; ++c) acc += g[b*64+c] * fc_w[a*64+c];
    float v = (acc - bma[a]) * rsqrtf(bva[a] + EPSBN) * bga[a] + bba[a];
    h[b][a] = fmaxf(v, 0.f);
  }
  __syncthreads();

  int idx = blockIdx.x*256 + tid;
  int ci_l = idx & 31;
  int o    = (idx >> 5) & 31;
  int s    = (idx >> 10) % 9;
  int t2   = (idx >> 10) / 9;
  int cc   = t2 & 1, b = t2 >> 1;
  int ci   = cc*32 + ci_l;

  const float* hb = h[b];
  float zc = ch_b[ci], zs = sp_b[s];
  float z0 = k_b[0],  z1 = k_b[1];
  #pragma unroll
  for (int a = 0; a < 16; ++a){
    float hv = hb[a];
    zc += hv*ch_w[ci*16+a];
    zs += hv*sp_w[s*16+a];
    z0 += hv*k_w[a];
    z1 += hv*k_w[16+a];
  }
  float chv = 1.f/(1.f+expf(-zc));
  float spv = 1.f/(1.f+expf(-zs));
  float m = fmaxf(z0,z1);
  float e0 = expf(z0-m), e1 = expf(z1-m), inv = 1.f/(e0+e1);
  float ka0 = e0*inv, ka1 = e1*inv;
  float w0 = weight[(o*64+ci)*9+s];
  float w1 = weight[((32+o)*64+ci)*9+s];
  aggb[idx] = f2u(chv*spv*(ka0*w0 + ka1*w1));

  if (blockIdx.x == 0){
    int bb = tid >> 5, oo = tid & 31;
    float z = fil_b[oo];
    #pragma unroll
    for (int a = 0; a < 16; ++a) z += h[bb][a]*fil_w[oo*16+a];
    float f = 1.f/(1.f+expf(-z));
    float invs = rsqrtf(bn_v[oo] + EPSBN);
    sS[tid] = f * bn_g[oo] * invs;
    if (bb == 0) tT[oo] = bn_b[oo] - bn_m[oo]*bn_g[oo]*invs;
  }
}

// -------- K3: MFMA implicit-GEMM conv + BN + GELU --------
// grid 512 = exactly 2 blocks/CU; each block does 2 q-adjacent 16x32 tiles (4 phases).
// A-operand (aggb) staged in LDS: 4608 dwords per (b,cc) = 18 dwords/thread (R4 bug: was 9).
// X tile + A buffer for the next phase loaded to regs BEFORE each kloop (latency hidden).
// Phase order: (A,cc0) (A,cc1) (B,cc1) (B,cc0) -> A-buffer restaged only 3x.
#define XT_STRIDE 40   // 32 ci + 8 pad halfwords (80 B rows)
#define AG_STRIDE 36   // halfwords per n-row of LDS A (72 B -> 2-way banks = free)

__global__ __launch_bounds__(256) void k_conv(const unsigned short* __restrict__ xup,
                                              const unsigned short* __restrict__ aggb,
                                              const float* __restrict__ sS,
                                              const float* __restrict__ tT,
                                              float* __restrict__ out)
{
  __shared__ unsigned short xt[18*34*XT_STRIDE];   // 48960 B
  __shared__ unsigned short agA[9*32*AG_STRIDE];   // 20736 B
  __shared__ float sSs[32], tTs[32];

  int tid = threadIdx.x;
  int bi  = blockIdx.x;
  int sw  = ((bi & 7) << 6) + (bi >> 3);     // nwg=512 -> xcd*64 + idx (bijective; b == xcd)
  int b   = sw >> 6, t6 = sw & 63;
  int p0  = (t6 >> 2) * 16;
  int qA  = (t6 & 3) * 64;                   // tiles at qA and qA+32
  int lane = tid & 63, wv = tid >> 6;
  if (tid < 32){ sSs[tid] = sS[b*32+tid]; tTs[tid] = tT[tid]; }

  int n = lane & 31, kq = lane >> 5;
  int rhalf = n >> 4, qb = n & 15, wrow = wv*4;

  const short8 zero8 = {0,0,0,0,0,0,0,0};
  const unsigned short* xbase = xup + (((size_t)(b*4)) << 20);
  const unsigned int*   agg32 = (const unsigned int*)(aggb + (size_t)(b*2)*9216);

  f32x16 acc[4];
  #pragma unroll
  for (int i = 0; i < 16; ++i){ acc[0][i]=0.f; acc[1][i]=0.f; acc[2][i]=0.f; acc[3][i]=0.f; }

  short8 cur[10];
  unsigned int ar[18];

  auto loadx = [&](int q0, int cc){
    const unsigned short* xb = xbase + (((size_t)(cc*2)) << 20);
    #pragma unroll
    for (int k = 0; k < 10; ++k){
      int e = tid + (k << 8); if (e >= 2448) e -= 2448;   // wrap dupes benign
      int rr = e / 136, rem = e - rr*136;
      int qq = rem >> 2, k2 = (rem >> 1) & 1, kqe = rem & 1;
      int gr = p0 - 1 + rr, gq = q0 - 1 + qq;
      bool v = ((unsigned)gr < 256u) && ((unsigned)gq < 256u);
      cur[k] = zero8;
      if (v) cur[k] = *(const short8*)&xb[(k2 << 20) + (gr*256 + gq)*16 + kqe*8];
    }
  };
  auto commitx = [&](){
    #pragma unroll
    for (int k = 0; k < 10; ++k){
      int e = tid + (k << 8); if (e >= 2448) e -= 2448;
      int rr = e / 136, rem = e - rr*136;
      int qq = rem >> 2, k2 = (rem >> 1) & 1, kqe = rem & 1;
      *(short8*)&xt[(rr*34 + qq)*XT_STRIDE + k2*16 + kqe*8] = cur[k];
    }
  };
  auto loada = [&](int cc){
    const unsigned int* s = agg32 + cc*4608;
    #pragma unroll
    for (int k = 0; k < 18; ++k) ar[k] = s[tid + (k << 8)];
  };
  auto commita = [&](){
    unsigned int* d32 = (unsigned int*)agA;
    #pragma unroll
    for (int k = 0; k < 18; ++k){
      int e = tid + (k << 8);                 // e = s*512 + nn*16 + c2   (4608 dwords)
      int c2 = e & 15, nn = (e >> 4) & 31, s = e >> 9;
      d32[s*(32*(AG_STRIDE/2)) + nn*(AG_STRIDE/2) + c2] = ar[k];
    }
  };

  auto kloop = [&](){
    #pragma unroll
    for (int s = 0; s < 9; ++s){
      const unsigned short* arow = &agA[(s*32 + n)*AG_STRIDE + kq*8];
      short8 a0, a1;
      *(short4v*)&a0        = *(const short4v*)&arow[0];
      *(((short4v*)&a0)+1)  = *(const short4v*)&arow[4];
      *(short4v*)&a1        = *(const short4v*)&arow[16];
      *(((short4v*)&a1)+1)  = *(const short4v*)&arow[20];
      const int ky = s/3, kx = s - ky*3;
      #pragma unroll
      for (int tt = 0; tt < 4; ++tt){
        const int rp = tt >> 1, cb = tt & 1;
        const unsigned short* xrow =
          &xt[((wrow + 2*rp + rhalf + ky)*34 + cb*16 + qb + kx)*XT_STRIDE + kq*8];
        short8 bv0 = *(const short8*)&xrow[0];
        short8 bv1 = *(const short8*)&xrow[16];
        acc[tt] = __builtin_amdgcn_mfma_f32_32x32x16_bf16(a0, bv0, acc[tt], 0, 0, 0);
        acc[tt] = __builtin_amdgcn_mfma_f32_32x32x16_bf16(a1, bv1, acc[tt], 0, 0, 0);
      }
    }
  };

  auto epi = [&](int q0){
    #pragma unroll
    for (int tt = 0; tt < 4; ++tt){
      int rp = tt >> 1, cb = tt & 1;
      int p = p0 + wrow + 2*rp + rhalf;
      int q = q0 + cb*16 + qb;
      #pragma unroll
      for (int r = 0; r < 16; ++r){
        int o = (r & 3) + 8*(r >> 2) + 4*kq;
        float valv = acc[tt][r]*sSs[o] + tTs[o];
        out[(((size_t)(b*32+o)) << 16) + (p << 8) + q] =
          0.5f*valv*(1.f + erff(valv*0.70710678118f));
      }
    }
  };

  // ---- phase pipeline ----
  loadx(qA, 0); loada(0);
  commitx(); commita();
  loadx(qA, 1); loada(1);            // in flight during phase 0
  __syncthreads();
  kloop();                            // phase 0: tile A, cc0
  __syncthreads();
  commitx(); commita();
  loadx(qA+32, 1);                    // in flight during phase 1 (A stays cc1)
  __syncthreads();
  kloop();                            // phase 1: tile A, cc1
  epi(qA);
  #pragma unroll
  for (int i = 0; i < 16; ++i){ acc[0][i]=0.f; acc[1][i]=0.f; acc[2][i]=0.f; acc[3][i]=0.f; }
  __syncthreads();
  commitx();
  loadx(qA+32, 0); loada(0);          // in flight during phase 2
  __syncthreads();
  kloop();                            // phase 2: tile B, cc1 (agA still cc1)
  __syncthreads();
  commitx(); commita();
  __syncthreads();
  kloop();                            // phase 3: tile B, cc0
  epi(qA+32);
}

extern "C" void kernel_launch(void* const* d_in, const int* in_sizes, int n_in,
                              void* d_out, int out_size, void* d_ws, size_t ws_size,
                              hipStream_t stream)
{
  const float* x     = (const float*)d_in[0];
  const float* fc_w  = (const float*)d_in[1];
  const float* bga   = (const float*)d_in[2];
  const float* bba   = (const float*)d_in[3];
  const float* bma   = (const float*)d_in[4];
  const float* bva   = (const float*)d_in[5];
  const float* ch_w  = (const float*)d_in[6];
  const float* ch_b  = (const float*)d_in[7];
  const float* fil_w = (const float*)d_in[8];
  const float* fil_b = (const float*)d_in[9];
  const float* sp_w  = (const float*)d_in[10];
  const float* sp_b  = (const float*)d_in[11];
  const float* k_w   = (const float*)d_in[12];
  const float* k_b   = (const float*)d_in[13];
  const float* weight= (const float*)d_in[14];
  const float* bn_g  = (const float*)d_in[15];
  const float* bn_b  = (const float*)d_in[16];
  const float* bn_m  = (const float*)d_in[17];
  const float* bn_v  = (const float*)d_in[18];

  char* ws = (char*)d_ws;
  float* g   = (float*)(ws + WS_G);
  float* sS  = (float*)(ws + WS_S);
  float* tT  = (float*)(ws + WS_T);
  unsigned short* aggb = (unsigned short*)(ws + WS_AGGB);
  unsigned short* xup  = (unsigned short*)(ws + WS_XUP);
  float* out = (float*)d_out;

  hipMemsetAsync(g, 0, 512*sizeof(float), stream);
  hipLaunchKernelGGL(k_up,   dim3(1024), dim3(256), 0, stream, x, (unsigned int*)xup, g);
  hipLaunchKernelGGL(k_aggw, dim3(576),  dim3(256), 0, stream, g, fc_w, bga, bba, bma, bva,
                     ch_w, ch_b, fil_w, fil_b, sp_w, sp_b, k_w, k_b,
                     bn_g, bn_b, bn_m, bn_v, weight, aggb, sS, tT);
  hipLaunchKernelGGL(k_conv, dim3(512),  dim3(256), 0, stream, xup, aggb, sS, tT, out);
}